// Round 2
// baseline (239.419 us; speedup 1.0000x reference)
//
#include <hip/hip_runtime.h>

// ChessMultiStageAttention: B=4096 fused blocks of (pos-add, LN, QKV, 8-head
// attention S=64 D=8 with chess bias, out-proj, residual). f32 I/O, bf16 MFMA
// internally (16x16x32_bf16), f32 accumulation. One 256-thread WG per batch.
//
// MFMA fragment layouts (m89-verified):
//   A: lane holds row m=lane&15, k = (lane>>4)*8 + j  (8 bf16, ds_read_b128)
//   B: lane holds col n=lane&15, k = (lane>>4)*8 + j
//   C/D: col = lane&15, row = (lane>>4)*4 + reg
// => every GEMM operand is stored [out-dim][K] with K contiguous.

typedef __attribute__((ext_vector_type(8))) __bf16 bfrag;
typedef __attribute__((ext_vector_type(4))) __bf16 bf4;
typedef __attribute__((ext_vector_type(4))) float f32x4;

#define MFMA16(a, b, c) __builtin_amdgcn_mfma_f32_16x16x32_bf16((a), (b), (c), 0, 0, 0)

static __device__ __forceinline__ bfrag bsplat(float v) {
  bfrag z;
#pragma unroll
  for (int i = 0; i < 8; i++) z[i] = (__bf16)v;
  return z;
}

// load 8 consecutive f32 from global, convert to a bf16 MFMA fragment
static __device__ __forceinline__ bfrag cvt8(const float* __restrict__ p) {
  float4 a = *(const float4*)p, b = *(const float4*)(p + 4);
  bfrag r;
  r[0] = (__bf16)a.x; r[1] = (__bf16)a.y; r[2] = (__bf16)a.z; r[3] = (__bf16)a.w;
  r[4] = (__bf16)b.x; r[5] = (__bf16)b.y; r[6] = (__bf16)b.z; r[7] = (__bf16)b.w;
  return r;
}

__global__ __launch_bounds__(256, 2) void chess_attn_kernel(
    const float* __restrict__ xg,    const float* __restrict__ posg,
    const float* __restrict__ gam,   const float* __restrict__ bet,
    const float* __restrict__ qkvw,  const float* __restrict__ qkvb,
    const float* __restrict__ outw,  const float* __restrict__ outb,
    const float* __restrict__ biasg, float* __restrict__ outg) {
  // LDS: 17152 + 17408 + 9216 + 9216 + 9216 + 512 = 62720 B (2 WG/CU)
  __shared__ float XPRE[64][67];                                 // x+pos (f32), [s][e]
  __shared__ __attribute__((aligned(16))) __bf16 QK[64][136];    // q: [s][0..63], k: [t][64..127]
  __shared__ __attribute__((aligned(16))) __bf16 VT[64][72];     // v^T: [(h,d)][t]
  __shared__ __attribute__((aligned(16))) __bf16 XNAO[64][72];   // XN (stage C-D) / AO (stage E-F)
  __shared__ __attribute__((aligned(16))) __bf16 P[4][16][72];   // per-wave P tile [s_local][t]
  __shared__ float MU[64];
  __shared__ float RS[64];

  const int tid  = threadIdx.x;
  const int lane = tid & 63;
  const int w    = tid >> 6;        // wave id 0..3
  const int b    = blockIdx.x;
  const float LN2I = 1.4426950408889634f;            // log2(e)
  const float SCL2 = 0.35355339059327373f * LN2I;    // (1/sqrt(8))*log2(e)

  // ---- Stage A: x + pos_embed -> XPRE[s][e] f32 (transpose from [e][s]) ----
  {
    const int e  = tid >> 2;         // channel
    const int s0 = (tid & 3) * 16;   // position chunk
    const float4* px = (const float4*)(xg + ((size_t)b * 64 + e) * 64 + s0);
    const float4* pp = (const float4*)(posg + (size_t)e * 64 + s0);
#pragma unroll
    for (int v = 0; v < 4; v++) {
      float4 xv = px[v], pv = pp[v];
      XPRE[s0 + v * 4 + 0][e] = xv.x + pv.x;
      XPRE[s0 + v * 4 + 1][e] = xv.y + pv.y;
      XPRE[s0 + v * 4 + 2][e] = xv.z + pv.z;
      XPRE[s0 + v * 4 + 3][e] = xv.w + pv.w;
    }
  }
  __syncthreads();

  // ---- Stage B: LayerNorm stats, 4 threads per row + shfl reduce ----
  {
    const int s = tid >> 2, q = tid & 3;
    float sum = 0.f, ss = 0.f;
#pragma unroll
    for (int i = 0; i < 16; i++) {
      float f = XPRE[s][q * 16 + i];
      sum += f; ss += f * f;
    }
    sum += __shfl_xor(sum, 1); ss += __shfl_xor(ss, 1);
    sum += __shfl_xor(sum, 2); ss += __shfl_xor(ss, 2);
    if (q == 0) {
      float mu  = sum * 0.015625f;
      float var = ss * 0.015625f - mu * mu;
      MU[s] = mu;
      RS[s] = __builtin_amdgcn_rsqf(var + 1e-5f);
    }
  }
  __syncthreads();

  // ---- Stage C: x_norm -> XNAO[s][e] (bf16) ----
  {
    const int s = tid >> 2, c0 = (tid & 3) * 16;
    const float mu = MU[s], rs = RS[s];
#pragma unroll
    for (int i = 0; i < 16; i++) {
      int c = c0 + i;
      XNAO[s][c] = (__bf16)((XPRE[s][c] - mu) * rs * gam[c] + bet[c]);
    }
  }
  __syncthreads();

  // ---- Stage D: QKV projection. Wave w covers n in [48w, 48w+48) ----
  {
    const int m = lane & 15;
    const int g = lane >> 4;
    bfrag A0[4], A1[4];
#pragma unroll
    for (int mt = 0; mt < 4; mt++) {
      A0[mt] = *(const bfrag*)&XNAO[mt * 16 + m][g * 8];
      A1[mt] = *(const bfrag*)&XNAO[mt * 16 + m][32 + g * 8];
    }
#pragma unroll
    for (int nt = 0; nt < 3; nt++) {
      const int nb = w * 48 + nt * 16;
      const int n  = nb + m;
      bfrag B0 = cvt8(qkvw + (size_t)n * 64 + g * 8);
      bfrag B1 = cvt8(qkvw + (size_t)n * 64 + 32 + g * 8);
      const float qb = qkvb[n];
#pragma unroll
      for (int mt = 0; mt < 4; mt++) {
        f32x4 c = {0.f, 0.f, 0.f, 0.f};
        c = MFMA16(A0[mt], B0, c);
        c = MFMA16(A1[mt], B1, c);
        if (nb < 128) {               // q or k -> QK[s][n]
#pragma unroll
          for (int r = 0; r < 4; r++)
            QK[mt * 16 + g * 4 + r][n] = (__bf16)(c[r] + qb);
        } else {                      // v -> VT[(h,d)][t], transposed, 8B packed
          bf4 pk;
#pragma unroll
          for (int r = 0; r < 4; r++) pk[r] = (__bf16)(c[r] + qb);
          *(bf4*)&VT[n - 128][mt * 16 + g * 4] = pk;
        }
      }
    }
  }
  __syncthreads();

  // ---- Stage E: attention, 2 heads per wave (h = w, w+4) ----
  const bfrag ZF = bsplat(0.f);
#pragma unroll 1
  for (int hl = 0; hl < 2; hl++) {
    const int h = w + hl * 4;
    const int m = lane & 15;
    const int g = lane >> 4;
    // B-frags for scores: k-matrix rows [t][d], K=8 real, zero-pad to 32
    bfrag BK[4];
#pragma unroll
    for (int nt = 0; nt < 4; nt++)
      BK[nt] = (lane < 16) ? *(const bfrag*)&QK[nt * 16 + m][64 + h * 8] : ZF;
    // B-frags for PV: cols 0..7 = v, col 8 = ones (row-sum trick), rest 0
    bfrag BV[2];
#pragma unroll
    for (int kf = 0; kf < 2; kf++) {
      if (m < 8)       BV[kf] = *(const bfrag*)&VT[h * 8 + m][kf * 32 + g * 8];
      else if (m == 8) BV[kf] = bsplat(1.f);
      else             BV[kf] = ZF;
    }
#pragma unroll 1
    for (int mt = 0; mt < 4; mt++) {
      bfrag AQ = (lane < 16) ? *(const bfrag*)&QK[mt * 16 + m][h * 8] : ZF;
      // scores -> exp2(scale*s + bias) -> unnormalized P (bf16, LDS)
#pragma unroll
      for (int nt = 0; nt < 4; nt++) {
        f32x4 c = {0.f, 0.f, 0.f, 0.f};
        c = MFMA16(AQ, BK[nt], c);
#pragma unroll
        for (int r = 0; r < 4; r++) {
          const int row = g * 4 + r;
          float bias_l = biasg[(size_t)(mt * 16 + row) * 64 + nt * 16 + m];
          float l = fmaf(bias_l, LN2I, c[r] * SCL2);
          P[w][row][nt * 16 + m] = (__bf16)__builtin_amdgcn_exp2f(l);
        }
      }
      __threadfence_block();   // same-wave LDS RAW: P writes -> A-frag reads
      bfrag AP0 = *(const bfrag*)&P[w][m][g * 8];
      bfrag AP1 = *(const bfrag*)&P[w][m][32 + g * 8];
      f32x4 oo = {0.f, 0.f, 0.f, 0.f};
      oo = MFMA16(AP0, BV[0], oo);
      oo = MFMA16(AP1, BV[1], oo);
      // col 8 holds row-sums; normalize and write AO[s][(h,d)]
#pragma unroll
      for (int r = 0; r < 4; r++) {
        float sum = __shfl(oo[r], (lane & 48) | 8);
        float val = oo[r] * __builtin_amdgcn_rcpf(sum);
        if (m < 8) XNAO[mt * 16 + g * 4 + r][h * 8 + m] = (__bf16)val;
      }
    }
  }
  __syncthreads();

  // ---- Stage F: out-proj (transposed: OP[e][s] = out_w @ AO^T) + residual ----
  {
    const int m  = lane & 15;
    const int g  = lane >> 4;
    const int sc = w * 16 + m;    // this wave's 16 positions (N dim)
    bfrag BO0 = *(const bfrag*)&XNAO[sc][g * 8];
    bfrag BO1 = *(const bfrag*)&XNAO[sc][32 + g * 8];
#pragma unroll
    for (int mt = 0; mt < 4; mt++) {
      bfrag AW0 = cvt8(outw + (size_t)(mt * 16 + m) * 64 + g * 8);
      bfrag AW1 = cvt8(outw + (size_t)(mt * 16 + m) * 64 + 32 + g * 8);
      f32x4 c = {0.f, 0.f, 0.f, 0.f};
      c = MFMA16(AW0, BO0, c);
      c = MFMA16(AW1, BO1, c);
#pragma unroll
      for (int r = 0; r < 4; r++) {
        const int e = mt * 16 + g * 4 + r;
        outg[((size_t)b * 64 + e) * 64 + sc] = c[r] + outb[e] + XPRE[sc][e];
      }
    }
  }
}

extern "C" void kernel_launch(void* const* d_in, const int* in_sizes, int n_in,
                              void* d_out, int out_size, void* d_ws, size_t ws_size,
                              hipStream_t stream) {
  const float* xg   = (const float*)d_in[0];
  const float* pos  = (const float*)d_in[1];
  const float* gam  = (const float*)d_in[2];
  const float* bet  = (const float*)d_in[3];
  const float* qkvw = (const float*)d_in[4];
  const float* qkvb = (const float*)d_in[5];
  const float* outw = (const float*)d_in[6];
  const float* outb = (const float*)d_in[7];
  const float* cb   = (const float*)d_in[8];
  float* out = (float*)d_out;
  const int B = in_sizes[0] / (64 * 64);   // 4096
  hipLaunchKernelGGL(chess_attn_kernel, dim3(B), dim3(256), 0, stream,
                     xg, pos, gam, bet, qkvw, qkvb, outw, outb, cb, out);
}